// Round 14
// baseline (469.719 us; speedup 1.0000x reference)
//
#include <hip/hip_runtime.h>
#include <cstdint>
#include <cstddef>

#define M_DIM 4096
#define N_DIM 16384
#define K_DIM 4096
#define NBLK_Q 128

#define BM 256
#define BN 256
#define BK 32
#define KSTEPS (K_DIM / BK)  // 128
#define BUFB 8192            // A-slab only
#define NBUF 4               // 32 KB LDS

typedef int i32x4 __attribute__((ext_vector_type(4)));
typedef int i32x16 __attribute__((ext_vector_type(16)));

#define SFENCE() __builtin_amdgcn_sched_barrier(0)
#define BAR() __builtin_amdgcn_s_barrier()
#define WAITVM(n) asm volatile("s_waitcnt vmcnt(" #n ")")
#define WAITLG0() asm volatile("s_waitcnt lgkmcnt(0)")

// ---- pre-pass 1: per-row int8 quant of x, scattered into staged-tile order ----
// A8S = [mtile 16][k32 128][m32 8][kg 2][row 32][16B]
__global__ __launch_bounds__(256) void quant_x(const float* __restrict__ x,
                                               char* __restrict__ A8S,
                                               float* __restrict__ sxr) {
  const int m = blockIdx.x;
  const int t = threadIdx.x;
  const float* xr = x + (size_t)m * K_DIM + t * 16;
  float4 v[4];
#pragma unroll
  for (int i = 0; i < 4; ++i) v[i] = ((const float4*)xr)[i];
  float amax = 0.f;
#pragma unroll
  for (int i = 0; i < 4; ++i)
    amax = fmaxf(amax, fmaxf(fmaxf(fabsf(v[i].x), fabsf(v[i].y)),
                             fmaxf(fabsf(v[i].z), fabsf(v[i].w))));
#pragma unroll
  for (int off = 32; off; off >>= 1) amax = fmaxf(amax, __shfl_xor(amax, off, 64));
  __shared__ float wmax[4];
  if ((t & 63) == 0) wmax[t >> 6] = amax;
  __syncthreads();
  amax = fmaxf(fmaxf(wmax[0], wmax[1]), fmaxf(wmax[2], wmax[3]));
  const float inv = 127.0f / amax;
  if (t == 0) sxr[m] = amax / 127.0f;
  unsigned d[4];
#pragma unroll
  for (int i = 0; i < 4; ++i) {
    int q0 = (int)rintf(v[i].x * inv), q1 = (int)rintf(v[i].y * inv);
    int q2 = (int)rintf(v[i].z * inv), q3 = (int)rintf(v[i].w * inv);
    d[i] = (q0 & 0xff) | ((q1 & 0xff) << 8) | ((q2 & 0xff) << 16) | ((q3 & 0xff) << 24);
  }
  const int k32 = t >> 1, kg = t & 1;
  const int mtile = m >> 8, mm = m & 255, m32 = mm >> 5, r = mm & 31;
  int4* dst = (int4*)(A8S + ((size_t)(mtile * 128 + k32)) * 8192 + m32 * 1024 + kg * 512 + r * 16);
  *dst = make_int4(d[0], d[1], d[2], d[3]);
}

// ---- pre-pass 2: W requant to per-column scale, staged-tile order ----
// B8S = [ntile 64][k32 128][n32 8][kg 2][col 32][16B]
__global__ __launch_bounds__(256) void pack_w8(const int* __restrict__ qs,
                                               const float* __restrict__ scales,
                                               char* __restrict__ B8S,
                                               float* __restrict__ swc) {
  const int o = blockIdx.x * 4 + (threadIdx.x >> 6);
  const int l = threadIdx.x & 63;
  const float s0 = scales[(size_t)o * NBLK_Q + l];
  const float s1 = scales[(size_t)o * NBLK_Q + 64 + l];
  float S = fmaxf(s0, s1);
#pragma unroll
  for (int off = 32; off; off >>= 1) S = fmaxf(S, __shfl_xor(S, off, 64));
  if (l == 0) swc[o] = S;
  const float rS = 1.0f / S;
  const int nt = o >> 8, col = o & 255, n32 = col >> 5, c = col & 31;
#pragma unroll
  for (int h = 0; h < 2; ++h) {
    const int nb = l + 64 * h;
    const float ratio = ((h == 0) ? s0 : s1) * rS;
    const int4* q = (const int4*)(qs + ((size_t)o * NBLK_Q + nb) * 32);
    unsigned d[8];
#pragma unroll
    for (int g = 0; g < 8; ++g) {
      int4 v = q[g];
      int a0 = (int)rintf((float)v.x * ratio);
      int a1 = (int)rintf((float)v.y * ratio);
      int a2 = (int)rintf((float)v.z * ratio);
      int a3 = (int)rintf((float)v.w * ratio);
      d[g] = (a0 & 0xff) | ((a1 & 0xff) << 8) | ((a2 & 0xff) << 16) | ((a3 & 0xff) << 24);
    }
    char* dst = B8S + ((size_t)(nt * 128 + nb)) * 8192 + n32 * 1024 + c * 16;
    ((int4*)dst)[0] = make_int4(d[0], d[1], d[2], d[3]);
    ((int4*)(dst + 512))[0] = make_int4(d[4], d[5], d[6], d[7]);
  }
}

// ---- main GEMM: A via LDS, B via L2-direct register loads, pure i8 MFMA ----
// 256x256, BK=32, 8 waves 2Mx4N, per-wave 128x64 = 4x2 of 32x32, 8 MFMA/step.
// Pipe rebalance (R12 was LDS-bound): B-frags load DIRECTLY from L2 (B8S
// staged-order: each frag = coalesced 1KB instr, addr = base + l*16). Per-step
// LDS = A 32KB read + 8KB write = 357 cy, L2 = 24KB = 430 cy, MFMA 586 cy.
// PIPELINE CONTRACT (R13 bug was violating it in the prologue):
//   - LDS buf t&3 holds A-slab of tile t.
//   - At STEP(kt): GAC holds tile kt+2 (loaded as GAN at STEP(kt-2);
//     prologue seeds GAC = tile 2). ds_write GAC -> buf (kt+2)&3, whose
//     prior tile's reads finished >= 2 barriers ago.
//   - STEP(kt) reads A-frags(kt+1) from buf (kt+1)&3 (written one barrier
//     ago) and B-frags(kt+1) from L2; MFMA consumes frags(kt) (regs).
//   - Queue at STEP top = [NB0(kt), NB1(kt), GAN(kt+2)] -> WAITVM(1) lands
//     both B-frags, A-stage keeps flying. After MFMA, queue = [GAN(kt+2),
//     NB0(kt+1), NB1(kt+1), GAN(kt+3)] -> WAITVM(3) lands exactly GAC's data
//     before its ds_write. vmcnt never 0 in loop.
//   - Prologue: tiles 0,1 -> bufs 0,1 ONLY; gaC = tile 2. (R13 staged tile 2
//     into LDS AND set gaC = tile 3 -> STEP(0) clobbered buf 2 with tile 3:
//     absmax 64 = one-K-tile error. Fixed.)
// Tail: qf/qa clamped to 127; dup writes land in buffers whose future reads
// are dead (traced kt=125..127). Named reg sets only (rule #20).
// Grid: XCD-partitioned (FETCH 295MB proven R11/R12).
__global__ __launch_bounds__(512, 2) void gemm_i8(
    const char* __restrict__ A8S, const char* __restrict__ B8S,
    const float* __restrict__ sxr, const float* __restrict__ swc,
    const float* __restrict__ bias, float* __restrict__ C) {
  __shared__ __align__(16) char lds[NBUF * BUFB];  // 32 KB

  const int tid = threadIdx.x;
  const int w = tid >> 6;
  const int l = tid & 63;
  const int wm = w >> 2;  // 0..1
  const int wn = w & 3;   // 0..3

  const int bid = blockIdx.x;
  const int xcd = bid & 7;
  const int k = bid >> 3;
  const int mtile = xcd * 2 + (k & 1);
  const int ntile = k >> 1;
  const int brow = mtile * BM;
  const int bcol = ntile * BN;

  const char* srcA = A8S + (size_t)mtile * 128 * 8192 + w * 1024 + l * 16;   // A-stage
  const char* srcBf = B8S + (size_t)ntile * 128 * 8192 + wn * 2048 + l * 16; // B-frags
  const int doffA = w * 1024 + l * 16;          // A-stage LDS dest
  const int roffA = wm * 4096 + l * 16;         // A-frag LDS base

  i32x16 acc[4][2] = {};
  i32x4 ca0, ca1, ca2, ca3, na0, na1, na2, na3;  // A-frag dbuf (named)
  i32x4 cb0, cb1, nb0, nb1;                      // B-frag dbuf (named)
  int4 gaC, gaN;                                 // A-stage reg dbuf

  // ---- prologue: tiles 0,1 -> bufs 0,1; gaC = tile 2; frags(0) ----
  {
    int4 t0 = *(const int4*)(srcA);
    int4 t1 = *(const int4*)(srcA + 8192);
    WAITVM(0);
    *(int4*)(lds + doffA) = t0;
    *(int4*)(lds + BUFB + doffA) = t1;
    WAITLG0();
    SFENCE(); BAR(); SFENCE();
    // B-frags(0); A-stage reg = tile 2
    cb0 = *(const i32x4*)(srcBf);
    cb1 = *(const i32x4*)(srcBf + 1024);
    gaC = *(const int4*)(srcA + 2 * 8192);
    // A-frags(0) from buf0
    ca0 = *(const i32x4*)(lds + roffA);
    ca1 = *(const i32x4*)(lds + roffA + 1024);
    ca2 = *(const i32x4*)(lds + roffA + 2048);
    ca3 = *(const i32x4*)(lds + roffA + 3072);
    WAITVM(1);   // cb0, cb1 landed (gaC may fly)
    WAITLG0();   // ca landed
    SFENCE();
  }

#define STEP(KT, CA0, CA1, CA2, CA3, NA0, NA1, NA2, NA3, CB0, CB1, NB0, NB1, GAC, GAN) \
  do {                                                                         \
    WAITVM(1); /* B-frags(KT) landed; A-stage(KT+2) may fly */                 \
    const char* rb = lds + (((KT) + 1) & 3) * BUFB;                            \
    NA0 = *(const i32x4*)(rb + roffA);                                         \
    NA1 = *(const i32x4*)(rb + roffA + 1024);                                  \
    NA2 = *(const i32x4*)(rb + roffA + 2048);                                  \
    NA3 = *(const i32x4*)(rb + roffA + 3072);                                  \
    {                                                                          \
      const int qf = ((KT) + 1 > KSTEPS - 1) ? (KSTEPS - 1) : ((KT) + 1);      \
      NB0 = *(const i32x4*)(srcBf + (size_t)qf * 8192);                        \
      NB1 = *(const i32x4*)(srcBf + (size_t)qf * 8192 + 1024);                 \
      const int qa = ((KT) + 3 > KSTEPS - 1) ? (KSTEPS - 1) : ((KT) + 3);      \
      GAN = *(const int4*)(srcA + (size_t)qa * 8192);                          \
    }                                                                          \
    SFENCE();                                                                  \
    __builtin_amdgcn_s_setprio(1);                                             \
    acc[0][0] = __builtin_amdgcn_mfma_i32_32x32x32_i8(CA0, CB0, acc[0][0], 0, 0, 0); \
    acc[0][1] = __builtin_amdgcn_mfma_i32_32x32x32_i8(CA0, CB1, acc[0][1], 0, 0, 0); \
    acc[1][0] = __builtin_amdgcn_mfma_i32_32x32x32_i8(CA1, CB0, acc[1][0], 0, 0, 0); \
    acc[1][1] = __builtin_amdgcn_mfma_i32_32x32x32_i8(CA1, CB1, acc[1][1], 0, 0, 0); \
    acc[2][0] = __builtin_amdgcn_mfma_i32_32x32x32_i8(CA2, CB0, acc[2][0], 0, 0, 0); \
    acc[2][1] = __builtin_amdgcn_mfma_i32_32x32x32_i8(CA2, CB1, acc[2][1], 0, 0, 0); \
    acc[3][0] = __builtin_amdgcn_mfma_i32_32x32x32_i8(CA3, CB0, acc[3][0], 0, 0, 0); \
    acc[3][1] = __builtin_amdgcn_mfma_i32_32x32x32_i8(CA3, CB1, acc[3][1], 0, 0, 0); \
    __builtin_amdgcn_s_setprio(0);                                             \
    SFENCE();                                                                  \
    WAITVM(3); /* GAC's tile (KT+2) landed; 3 newest still fly */              \
    {                                                                          \
      char* wb = lds + (((KT) + 2) & 3) * BUFB;                                \
      *(int4*)(wb + doffA) = GAC;                                              \
    }                                                                          \
    SFENCE();                                                                  \
    WAITLG0(); /* write visible (frag reads long done) */                      \
    SFENCE(); BAR(); SFENCE();                                                 \
  } while (0)

  for (int kt = 0; kt < KSTEPS; kt += 2) {
    STEP(kt, ca0, ca1, ca2, ca3, na0, na1, na2, na3, cb0, cb1, nb0, nb1, gaC, gaN);
    STEP(kt + 1, na0, na1, na2, na3, ca0, ca1, ca2, ca3, nb0, nb1, cb0, cb1, gaN, gaC);
  }
#undef STEP

  // epilogue: 32x32 C/D layout col = lane&31, row = (reg&3)+8*(reg>>2)+4*(lane>>5)
#pragma unroll
  for (int i = 0; i < 4; ++i) {
    const int rbx = brow + wm * 128 + i * 32 + 4 * (l >> 5);
#pragma unroll
    for (int j = 0; j < 2; ++j) {
      const int col = bcol + wn * 64 + j * 32 + (l & 31);
      const float Sw = swc[col];
      const float bv = bias[col];
#pragma unroll
      for (int r = 0; r < 16; ++r) {
        const int row = rbx + (r & 3) + 8 * (r >> 2);
        C[(size_t)row * N_DIM + col] = (float)acc[i][j][r] * (sxr[row] * Sw) + bv;
      }
    }
  }
}

// ---- fallback (ws too small): exact fp32, slow but correct ----
__global__ void naive_gemm(const float* __restrict__ x, const int* __restrict__ qs,
                           const float* __restrict__ scales, const float* __restrict__ bias,
                           float* __restrict__ y) {
  size_t idx = (size_t)blockIdx.x * 256 + threadIdx.x;
  if (idx >= (size_t)M_DIM * N_DIM) return;
  int o = (int)(idx % N_DIM);
  size_t m = idx / N_DIM;
  const float* xr = x + m * K_DIM;
  const int* q = qs + (size_t)o * K_DIM;
  const float* sc = scales + (size_t)o * NBLK_Q;
  float sum = 0.f;
  for (int nb = 0; nb < NBLK_Q; ++nb) {
    float s = sc[nb];
    float bs = 0.f;
#pragma unroll 8
    for (int b = 0; b < 32; ++b) bs += xr[nb * 32 + b] * (float)q[nb * 32 + b];
    sum += s * bs;
  }
  y[idx] = sum + bias[o];
}

extern "C" void kernel_launch(void* const* d_in, const int* in_sizes, int n_in,
                              void* d_out, int out_size, void* d_ws, size_t ws_size,
                              hipStream_t stream) {
  const float* x = (const float*)d_in[0];
  const int* qs = (const int*)d_in[1];
  const float* scales = (const float*)d_in[2];
  const float* bias = (const float*)d_in[3];
  float* y = (float*)d_out;

  const size_t A8_bytes = (size_t)M_DIM * K_DIM;   // 16 MB
  const size_t B8_bytes = (size_t)N_DIM * K_DIM;   // 64 MB
  const size_t SX_bytes = (size_t)M_DIM * 4;
  const size_t SW_bytes = (size_t)N_DIM * 4;

  if (ws_size < A8_bytes + B8_bytes + SX_bytes + SW_bytes) {
    size_t total = (size_t)M_DIM * N_DIM;
    naive_gemm<<<(unsigned)((total + 255) / 256), 256, 0, stream>>>(x, qs, scales, bias, y);
    return;
  }

  char* A8S = (char*)d_ws;
  char* B8S = A8S + A8_bytes;
  float* sxr = (float*)(B8S + B8_bytes);
  float* swc = (float*)((char*)sxr + SX_bytes);

  quant_x<<<M_DIM, 256, 0, stream>>>(x, A8S, sxr);
  pack_w8<<<N_DIM / 4, 256, 0, stream>>>(qs, scales, B8S, swc);
  gemm_i8<<<(M_DIM / BM) * (N_DIM / BN), 512, 0, stream>>>(A8S, B8S, sxr, swc, bias, y);
}

// Round 15
// 425.649 us; speedup vs baseline: 1.1035x; 1.1035x over previous
//
#include <hip/hip_runtime.h>
#include <cstdint>
#include <cstddef>

#define M_DIM 4096
#define N_DIM 16384
#define K_DIM 4096
#define NBLK_Q 128

#define BM 256
#define BN 256
#define BK 64
#define KTILES (K_DIM / BK)  // 64
#define BUFB 32768           // [A: ks0 8K | ks1 8K | B: ks0 8K | ks1 8K]
#define NBUF 2               // 64 KB LDS

typedef int i32x4 __attribute__((ext_vector_type(4)));
typedef int i32x16 __attribute__((ext_vector_type(16)));

#define SFENCE() __builtin_amdgcn_sched_barrier(0)
#define BAR() __builtin_amdgcn_s_barrier()
#define WAITVM(n) asm volatile("s_waitcnt vmcnt(" #n ")")
#define WAITLG0() asm volatile("s_waitcnt lgkmcnt(0)")

// ---- pre-pass 1: per-row int8 quant of x, staged-tile order ----
// A8S = [mtile 16][k32 128][m32 8][kg 2][row 32][16B]
__global__ __launch_bounds__(256) void quant_x(const float* __restrict__ x,
                                               char* __restrict__ A8S,
                                               float* __restrict__ sxr) {
  const int m = blockIdx.x;
  const int t = threadIdx.x;
  const float* xr = x + (size_t)m * K_DIM + t * 16;
  float4 v[4];
#pragma unroll
  for (int i = 0; i < 4; ++i) v[i] = ((const float4*)xr)[i];
  float amax = 0.f;
#pragma unroll
  for (int i = 0; i < 4; ++i)
    amax = fmaxf(amax, fmaxf(fmaxf(fabsf(v[i].x), fabsf(v[i].y)),
                             fmaxf(fabsf(v[i].z), fabsf(v[i].w))));
#pragma unroll
  for (int off = 32; off; off >>= 1) amax = fmaxf(amax, __shfl_xor(amax, off, 64));
  __shared__ float wmax[4];
  if ((t & 63) == 0) wmax[t >> 6] = amax;
  __syncthreads();
  amax = fmaxf(fmaxf(wmax[0], wmax[1]), fmaxf(wmax[2], wmax[3]));
  const float inv = 127.0f / amax;
  if (t == 0) sxr[m] = amax / 127.0f;
  unsigned d[4];
#pragma unroll
  for (int i = 0; i < 4; ++i) {
    int q0 = (int)rintf(v[i].x * inv), q1 = (int)rintf(v[i].y * inv);
    int q2 = (int)rintf(v[i].z * inv), q3 = (int)rintf(v[i].w * inv);
    d[i] = (q0 & 0xff) | ((q1 & 0xff) << 8) | ((q2 & 0xff) << 16) | ((q3 & 0xff) << 24);
  }
  const int k32 = t >> 1, kg = t & 1;
  const int mtile = m >> 8, mm = m & 255, m32 = mm >> 5, r = mm & 31;
  int4* dst = (int4*)(A8S + ((size_t)(mtile * 128 + k32)) * 8192 + m32 * 1024 + kg * 512 + r * 16);
  *dst = make_int4(d[0], d[1], d[2], d[3]);
}

// ---- pre-pass 2: W requant to per-column scale, staged-tile order ----
// B8S = [ntile 64][k32 128][n32 8][kg 2][col 32][16B]
__global__ __launch_bounds__(256) void pack_w8(const int* __restrict__ qs,
                                               const float* __restrict__ scales,
                                               char* __restrict__ B8S,
                                               float* __restrict__ swc) {
  const int o = blockIdx.x * 4 + (threadIdx.x >> 6);
  const int l = threadIdx.x & 63;
  const float s0 = scales[(size_t)o * NBLK_Q + l];
  const float s1 = scales[(size_t)o * NBLK_Q + 64 + l];
  float S = fmaxf(s0, s1);
#pragma unroll
  for (int off = 32; off; off >>= 1) S = fmaxf(S, __shfl_xor(S, off, 64));
  if (l == 0) swc[o] = S;
  const float rS = 1.0f / S;
  const int nt = o >> 8, col = o & 255, n32 = col >> 5, c = col & 31;
#pragma unroll
  for (int h = 0; h < 2; ++h) {
    const int nb = l + 64 * h;
    const float ratio = ((h == 0) ? s0 : s1) * rS;
    const int4* q = (const int4*)(qs + ((size_t)o * NBLK_Q + nb) * 32);
    unsigned d[8];
#pragma unroll
    for (int g = 0; g < 8; ++g) {
      int4 v = q[g];
      int a0 = (int)rintf((float)v.x * ratio);
      int a1 = (int)rintf((float)v.y * ratio);
      int a2 = (int)rintf((float)v.z * ratio);
      int a3 = (int)rintf((float)v.w * ratio);
      d[g] = (a0 & 0xff) | ((a1 & 0xff) << 8) | ((a2 & 0xff) << 16) | ((a3 & 0xff) << 24);
    }
    char* dst = B8S + ((size_t)(nt * 128 + nb)) * 8192 + n32 * 1024 + c * 16;
    ((int4*)dst)[0] = make_int4(d[0], d[1], d[2], d[3]);
    ((int4*)(dst + 512))[0] = make_int4(d[4], d[5], d[6], d[7]);
  }
}

// ---- main GEMM: 4-phase fine-interleave (m201/T3+T4 port), reg-staged i8 ----
// 256x256, BK=64, 8 waves 2Mx4N, per-wave 128x64 = 4x2 of 32x32, 16 MFMA/tile.
// PIPELINE CONTRACT:
//  - LDS buf kt&1 holds tile kt during its 4 phases.
//  - During tile kt: Scur regs (cA0,cA1,cB0,cB1) hold tile kt+1 (loaded during
//    kt-1; prologue seeds Scur = tile 1); phases P0..P3 issue the 4 loads of
//    tile kt+2 into Snxt (1 per phase, fixed cadence; index clamped at tail ->
//    dups land in buffers never read again).
//  - P3: WAITVM(4) leaves kt+2's 4 in flight, guarantees Scur (kt+1) landed;
//    4x ds_write Scur -> buf (kt+1)&1, whose last reads (tile kt-1, P3 pre-
//    region) retired at kt-1.P3's lgkm0, >=4 barriers ago. WAITLG0 + BAR makes
//    writes visible before kt+1's P0 reads.
//  - Phase p: {ds_read 2-4 frags (pre-bar: issues while other waves finish
//    p-1's MFMA); 1 stage-load; BAR; lgkm0; SFENCE; prio1; 4 MFMA; prio0; BAR}.
//    Phase split over (ih, ks): b-ks regs (bb0,bb1) held across the 2 ih-phases
//    -> zero re-reads, LDS totals unchanged vs R12 (0 bank conflicts layout).
//    ks0 accumulated for all i before ks1 (int add exact, order-free).
//  - vmcnt never 0 in the loop. Named reg sets only (rule #20).
// Grid: XCD-partitioned (FETCH 295MB proven R11/R12): XCD x owns mtiles
// {2x,2x+1} x all ntiles, pair-adjacent for B L2 sharing.
__global__ __launch_bounds__(512, 2) void gemm_i8(
    const char* __restrict__ A8S, const char* __restrict__ B8S,
    const float* __restrict__ sxr, const float* __restrict__ swc,
    const float* __restrict__ bias, float* __restrict__ C) {
  __shared__ __align__(16) char lds[NBUF * BUFB];  // 64 KB

  const int tid = threadIdx.x;
  const int w = tid >> 6;
  const int l = tid & 63;
  const int wm = w >> 2;  // 0..1
  const int wn = w & 3;   // 0..3

  const int bid = blockIdx.x;
  const int xcd = bid & 7;
  const int k = bid >> 3;
  const int mtile = xcd * 2 + (k & 1);
  const int ntile = k >> 1;
  const int brow = mtile * BM;
  const int bcol = ntile * BN;

  // stage sources: wave w moves chunk m32=w (A) / n32=w (B) of each k-slab.
  const char* srcA = A8S + (size_t)mtile * 128 * 8192 + w * 1024 + l * 16;
  const char* srcB = B8S + (size_t)ntile * 128 * 8192 + w * 1024 + l * 16;
  const int doff = w * 1024 + l * 16;        // stage dest within a ks-slab
  const int rA = wm * 4096 + l * 16;         // A-frag base (i-tile idx * 1024)
  const int rB = wn * 2048 + l * 16;         // B-frag base (j-tile idx * 1024)

  i32x16 acc[4][2] = {};
  i32x4 aa0, aa1, bb0, bb1;          // operand frags (reused across phases)
  int4 cA0, cA1, cB0, cB1;           // Scur: tile kt+1
  int4 nA0, nA1, nB0, nB1;           // Snxt: tile kt+2 (in flight)

  // ---- prologue: tile0 -> buf0; Scur = tile1 ----
  {
    int4 t0 = *(const int4*)(srcA);             // t0 A ks0
    int4 t1 = *(const int4*)(srcA + 8192);      // t0 A ks1
    int4 t2 = *(const int4*)(srcB);             // t0 B ks0
    int4 t3 = *(const int4*)(srcB + 8192);      // t0 B ks1
    WAITVM(0);
    *(int4*)(lds + doff) = t0;
    *(int4*)(lds + 8192 + doff) = t1;
    *(int4*)(lds + 16384 + doff) = t2;
    *(int4*)(lds + 24576 + doff) = t3;
    cA0 = *(const int4*)(srcA + 2 * 8192);      // tile1 A ks0
    cA1 = *(const int4*)(srcA + 3 * 8192);      // tile1 A ks1
    cB0 = *(const int4*)(srcB + 2 * 8192);      // tile1 B ks0
    cB1 = *(const int4*)(srcB + 3 * 8192);      // tile1 B ks1
    WAITLG0();
    SFENCE(); BAR(); SFENCE();
  }

#define TILE(KT, CA0, CA1, CB0, CB1, NA0, NA1, NB0, NB1)                       \
  do {                                                                         \
    const char* bb = lds + ((KT) & 1) * BUFB;                                  \
    char* nb = lds + (((KT) + 1) & 1) * BUFB;                                  \
    const int qn = ((KT) + 2 > KTILES - 1) ? (KTILES - 1) : ((KT) + 2);        \
    const size_t gq = (size_t)qn * 16384;                                      \
    /* P0: (ih0, ks0) */                                                       \
    aa0 = *(const i32x4*)(bb + rA);                                            \
    aa1 = *(const i32x4*)(bb + rA + 1024);                                     \
    bb0 = *(const i32x4*)(bb + 16384 + rB);                                    \
    bb1 = *(const i32x4*)(bb + 16384 + rB + 1024);                             \
    NA0 = *(const int4*)(srcA + gq);                                           \
    SFENCE(); BAR(); WAITLG0(); SFENCE();                                      \
    __builtin_amdgcn_s_setprio(1);                                             \
    acc[0][0] = __builtin_amdgcn_mfma_i32_32x32x32_i8(aa0, bb0, acc[0][0], 0, 0, 0); \
    acc[0][1] = __builtin_amdgcn_mfma_i32_32x32x32_i8(aa0, bb1, acc[0][1], 0, 0, 0); \
    acc[1][0] = __builtin_amdgcn_mfma_i32_32x32x32_i8(aa1, bb0, acc[1][0], 0, 0, 0); \
    acc[1][1] = __builtin_amdgcn_mfma_i32_32x32x32_i8(aa1, bb1, acc[1][1], 0, 0, 0); \
    __builtin_amdgcn_s_setprio(0);                                             \
    SFENCE(); BAR(); SFENCE();                                                 \
    /* P1: (ih1, ks0) — reuse bb0/bb1 */                                       \
    aa0 = *(const i32x4*)(bb + rA + 2048);                                     \
    aa1 = *(const i32x4*)(bb + rA + 3072);                                     \
    NA1 = *(const int4*)(srcA + gq + 8192);                                    \
    SFENCE(); BAR(); WAITLG0(); SFENCE();                                      \
    __builtin_amdgcn_s_setprio(1);                                             \
    acc[2][0] = __builtin_amdgcn_mfma_i32_32x32x32_i8(aa0, bb0, acc[2][0], 0, 0, 0); \
    acc[2][1] = __builtin_amdgcn_mfma_i32_32x32x32_i8(aa0, bb1, acc[2][1], 0, 0, 0); \
    acc[3][0] = __builtin_amdgcn_mfma_i32_32x32x32_i8(aa1, bb0, acc[3][0], 0, 0, 0); \
    acc[3][1] = __builtin_amdgcn_mfma_i32_32x32x32_i8(aa1, bb1, acc[3][1], 0, 0, 0); \
    __builtin_amdgcn_s_setprio(0);                                             \
    SFENCE(); BAR(); SFENCE();                                                 \
    /* P2: (ih0, ks1) */                                                       \
    aa0 = *(const i32x4*)(bb + 8192 + rA);                                     \
    aa1 = *(const i32x4*)(bb + 8192 + rA + 1024);                              \
    bb0 = *(const i32x4*)(bb + 24576 + rB);                                    \
    bb1 = *(const i32x4*)(bb + 24576 + rB + 1024);                             \
    NB0 = *(const int4*)(srcB + gq);                                           \
    SFENCE(); BAR(); WAITLG0(); SFENCE();                                      \
    __builtin_amdgcn_s_setprio(1);                                             \
    acc[0][0] = __builtin_amdgcn_mfma_i32_32x32x32_i8(aa0, bb0, acc[0][0], 0, 0, 0); \
    acc[0][1] = __builtin_amdgcn_mfma_i32_32x32x32_i8(aa0, bb1, acc[0][1], 0, 0, 0); \
    acc[1][0] = __builtin_amdgcn_mfma_i32_32x32x32_i8(aa1, bb0, acc[1][0], 0, 0, 0); \
    acc[1][1] = __builtin_amdgcn_mfma_i32_32x32x32_i8(aa1, bb1, acc[1][1], 0, 0, 0); \
    __builtin_amdgcn_s_setprio(0);                                             \
    SFENCE(); BAR(); SFENCE();                                                 \
    /* P3: (ih1, ks1) + commit Scur -> other buffer */                         \
    aa0 = *(const i32x4*)(bb + 8192 + rA + 2048);                              \
    aa1 = *(const i32x4*)(bb + 8192 + rA + 3072);                              \
    NB1 = *(const int4*)(srcB + gq + 8192);                                    \
    SFENCE(); BAR(); WAITLG0(); SFENCE();                                      \
    __builtin_amdgcn_s_setprio(1);                                             \
    acc[2][0] = __builtin_amdgcn_mfma_i32_32x32x32_i8(aa0, bb0, acc[2][0], 0, 0, 0); \
    acc[2][1] = __builtin_amdgcn_mfma_i32_32x32x32_i8(aa0, bb1, acc[2][1], 0, 0, 0); \
    acc[3][0] = __builtin_amdgcn_mfma_i32_32x32x32_i8(aa1, bb0, acc[3][0], 0, 0, 0); \
    acc[3][1] = __builtin_amdgcn_mfma_i32_32x32x32_i8(aa1, bb1, acc[3][1], 0, 0, 0); \
    __builtin_amdgcn_s_setprio(0);                                             \
    SFENCE();                                                                  \
    WAITVM(4); /* Scur (tile KT+1) landed; KT+2's 4 still fly */               \
    *(int4*)(nb + doff) = CA0;                                                 \
    *(int4*)(nb + 8192 + doff) = CA1;                                          \
    *(int4*)(nb + 16384 + doff) = CB0;                                         \
    *(int4*)(nb + 24576 + doff) = CB1;                                         \
    SFENCE();                                                                  \
    WAITLG0();                                                                 \
    SFENCE(); BAR(); SFENCE();                                                 \
  } while (0)

  for (int kt = 0; kt < KTILES; kt += 2) {
    TILE(kt, cA0, cA1, cB0, cB1, nA0, nA1, nB0, nB1);
    TILE(kt + 1, nA0, nA1, nB0, nB1, cA0, cA1, cB0, cB1);
  }
#undef TILE

  // epilogue: 32x32 C/D layout col = lane&31, row = (reg&3)+8*(reg>>2)+4*(lane>>5)
#pragma unroll
  for (int i = 0; i < 4; ++i) {
    const int rbx = brow + wm * 128 + i * 32 + 4 * (l >> 5);
#pragma unroll
    for (int j = 0; j < 2; ++j) {
      const int col = bcol + wn * 64 + j * 32 + (l & 31);
      const float Sw = swc[col];
      const float bv = bias[col];
#pragma unroll
      for (int r = 0; r < 16; ++r) {
        const int row = rbx + (r & 3) + 8 * (r >> 2);
        C[(size_t)row * N_DIM + col] = (float)acc[i][j][r] * (sxr[row] * Sw) + bv;
      }
    }
  }
}

// ---- fallback (ws too small): exact fp32, slow but correct ----
__global__ void naive_gemm(const float* __restrict__ x, const int* __restrict__ qs,
                           const float* __restrict__ scales, const float* __restrict__ bias,
                           float* __restrict__ y) {
  size_t idx = (size_t)blockIdx.x * 256 + threadIdx.x;
  if (idx >= (size_t)M_DIM * N_DIM) return;
  int o = (int)(idx % N_DIM);
  size_t m = idx / N_DIM;
  const float* xr = x + m * K_DIM;
  const int* q = qs + (size_t)o * K_DIM;
  const float* sc = scales + (size_t)o * NBLK_Q;
  float sum = 0.f;
  for (int nb = 0; nb < NBLK_Q; ++nb) {
    float s = sc[nb];
    float bs = 0.f;
#pragma unroll 8
    for (int b = 0; b < 32; ++b) bs += xr[nb * 32 + b] * (float)q[nb * 32 + b];
    sum += s * bs;
  }
  y[idx] = sum + bias[o];
}

extern "C" void kernel_launch(void* const* d_in, const int* in_sizes, int n_in,
                              void* d_out, int out_size, void* d_ws, size_t ws_size,
                              hipStream_t stream) {
  const float* x = (const float*)d_in[0];
  const int* qs = (const int*)d_in[1];
  const float* scales = (const float*)d_in[2];
  const float* bias = (const float*)d_in[3];
  float* y = (float*)d_out;

  const size_t A8_bytes = (size_t)M_DIM * K_DIM;   // 16 MB
  const size_t B8_bytes = (size_t)N_DIM * K_DIM;   // 64 MB
  const size_t SX_bytes = (size_t)M_DIM * 4;
  const size_t SW_bytes = (size_t)N_DIM * 4;

  if (ws_size < A8_bytes + B8_bytes + SX_bytes + SW_bytes) {
    size_t total = (size_t)M_DIM * N_DIM;
    naive_gemm<<<(unsigned)((total + 255) / 256), 256, 0, stream>>>(x, qs, scales, bias, y);
    return;
  }

  char* A8S = (char*)d_ws;
  char* B8S = A8S + A8_bytes;
  float* sxr = (float*)(B8S + B8_bytes);
  float* swc = (float*)((char*)sxr + SX_bytes);

  quant_x<<<M_DIM, 256, 0, stream>>>(x, A8S, sxr);
  pack_w8<<<N_DIM / 4, 256, 0, stream>>>(qs, scales, B8S, swc);
  gemm_i8<<<(M_DIM / BM) * (N_DIM / BN), 512, 0, stream>>>(A8S, B8S, sxr, swc, bias, y);
}